// Round 13
// baseline (101.337 us; speedup 1.0000x reference)
//
#include <hip/hip_runtime.h>
#include <hip/hip_bf16.h>
#include <math.h>

// Problem constants
#define B_  8
#define T_  2048
#define C_  128
#define H_  4
#define DH_ 32
#define BH_ 32
#define NTOK 16384
// (1/sqrt(32)) * log2(e): scores come out in log2 domain -> softmax via exp2
#define QSCALE_ 0.25503486f
#define NBLK 256

typedef __attribute__((ext_vector_type(8))) __bf16 bfrag;        // 4 VGPRs, MFMA A/B
typedef __attribute__((ext_vector_type(4))) float f32x4;
typedef __attribute__((ext_vector_type(16))) float f32x16;       // 32x32 MFMA C/D
typedef __attribute__((ext_vector_type(2))) unsigned int u32x2;
typedef __attribute__((ext_vector_type(4))) unsigned int u32x4;

__device__ __forceinline__ unsigned int pack2bf(float a, float b) {
    unsigned int ua = __float_as_uint(a);
    unsigned int ub = __float_as_uint(b);
    ua += 0x7fffu + ((ua >> 16) & 1u);   // RNE to bf16
    ub += 0x7fffu + ((ub >> 16) & 1u);
    return (ua >> 16) | (ub & 0xffff0000u);
}

__device__ __forceinline__ unsigned int cvtpk_bf16(float lo, float hi) {
    unsigned int r;
    asm("v_cvt_pk_bf16_f32 %0, %1, %2" : "=v"(r) : "v"(lo), "v"(hi));
    return r;
}

__device__ __forceinline__ float fast_exp2(float x) {
    float r;
    asm("v_exp_f32 %0, %1" : "=v"(r) : "v"(x));
    return r;
}

// Sense-reversal grid barrier, agent scope (what grid.sync() lowers to).
// All 256 blocks are co-resident by construction (1 block/CU).
__device__ __forceinline__ void gridbar(unsigned* cnt, unsigned* sense) {
    __syncthreads();                      // drains each wave's stores (vmcnt)
    if (threadIdx.x == 0) {
        const unsigned s = __hip_atomic_load(sense, __ATOMIC_RELAXED,
                                             __HIP_MEMORY_SCOPE_AGENT);
        const unsigned prev = __hip_atomic_fetch_add(cnt, 1u, __ATOMIC_ACQ_REL,
                                                     __HIP_MEMORY_SCOPE_AGENT);
        if (prev == NBLK - 1) {
            __hip_atomic_store(cnt, 0u, __ATOMIC_RELAXED, __HIP_MEMORY_SCOPE_AGENT);
            __hip_atomic_store(sense, s ^ 1u, __ATOMIC_RELEASE, __HIP_MEMORY_SCOPE_AGENT);
        } else {
            long spins = 0;
            while (__hip_atomic_load(sense, __ATOMIC_ACQUIRE,
                                     __HIP_MEMORY_SCOPE_AGENT) == s) {
                __builtin_amdgcn_s_sleep(2);
                if (++spins > (1L << 22)) break;   // safety valve: no hard hang
            }
        }
    }
    __syncthreads();
}

// ---------------------------------------------------------------------------
// MEGAKERNEL: phase 0 = W transposes; phase 1 = QKV projection; phase 2 =
// fused attention + out-projection (two round-11 virtual blocks per block).
// 256 blocks x 1024 threads = exactly 1 block/CU, 16 waves/CU.
// ---------------------------------------------------------------------------
__global__ __launch_bounds__(1024, 4)
void mega(const float* __restrict__ x, const float* __restrict__ Wqkv,
          const float* __restrict__ bqkv, const float* __restrict__ Wout,
          const float* __restrict__ bout,
          __hip_bfloat16* __restrict__ Qb, __hip_bfloat16* __restrict__ Kb,
          __hip_bfloat16* __restrict__ Vt, __hip_bfloat16* __restrict__ WqkvT,
          __hip_bfloat16* __restrict__ WoutT, float* __restrict__ out,
          unsigned* __restrict__ bar) {
    __shared__ float csm[2][4][64][17];       // 34.8 KB
    __shared__ unsigned int Osm[2][32][68];   // 17.4 KB

    const int bid = blockIdx.x;               // 0..255
    const int tid = threadIdx.x;              // 0..1023

    // ================= phase 0: W transposes (blocks 0..7) ================
    if (bid < 8) {
        const int idx = bid * 1024 + tid;     // 0..8191
        if (idx < 6144) {                     // WqkvT: n 0..383, k8 0..15
            const int n = idx >> 4, k8 = idx & 15;
            float v[8];
#pragma unroll
            for (int i = 0; i < 8; ++i) v[i] = Wqkv[(k8 * 8 + i) * 384 + n];
            u32x4 pk;
            pk.x = pack2bf(v[0], v[1]); pk.y = pack2bf(v[2], v[3]);
            pk.z = pack2bf(v[4], v[5]); pk.w = pack2bf(v[6], v[7]);
            *(u32x4*)(WqkvT + n * 128 + k8 * 8) = pk;
        } else {                              // WoutT: n 0..127, k8 0..15
            const int m = idx - 6144;
            const int n = m >> 4, k8 = m & 15;
            float v[8];
#pragma unroll
            for (int i = 0; i < 8; ++i) v[i] = Wout[(k8 * 8 + i) * 128 + n];
            u32x4 pk;
            pk.x = pack2bf(v[0], v[1]); pk.y = pack2bf(v[2], v[3]);
            pk.z = pack2bf(v[4], v[5]); pk.w = pack2bf(v[6], v[7]);
            *(u32x4*)(WoutT + n * 128 + k8 * 8) = pk;
        }
    }
    gridbar(bar, bar + 1);

    // ================= phase 1: QKV projection (64 tokens/block) ==========
    {
        const int w8   = tid >> 6;            // wave 0..15
        const int w    = w8 & 3;
        const int lane = tid & 63;
        const int qi   = lane & 15, grp = lane >> 4;
        const int mbase = bid * 64 + (w8 >> 2) * 16;

        const f32x4 zero = {0.f, 0.f, 0.f, 0.f};
        f32x4 acc[6] = {zero, zero, zero, zero, zero, zero};

        const float* xrow = x + (size_t)(mbase + qi) * 128;
        bfrag xf[4];
#pragma unroll
        for (int ks = 0; ks < 4; ++ks) {
            const float4 a = *(const float4*)(xrow + ks * 32 + grp * 8);
            const float4 b = *(const float4*)(xrow + ks * 32 + grp * 8 + 4);
            u32x4 pk;
            pk.x = cvtpk_bf16(a.x, a.y);
            pk.y = cvtpk_bf16(a.z, a.w);
            pk.z = cvtpk_bf16(b.x, b.y);
            pk.w = cvtpk_bf16(b.z, b.w);
            xf[ks] = __builtin_bit_cast(bfrag, pk);
        }

#pragma unroll
        for (int j = 0; j < 6; ++j) {
            const int nb = j * 4 + w;
#pragma unroll
            for (int ks = 0; ks < 4; ++ks) {
                const bfrag wf = *(const bfrag*)(WqkvT + (size_t)(nb * 16 + qi) * 128 + ks * 32 + grp * 8);
                if (j < 4) acc[j] = __builtin_amdgcn_mfma_f32_16x16x32_bf16(wf, xf[ks], acc[j], 0, 0, 0);
                else       acc[j] = __builtin_amdgcn_mfma_f32_16x16x32_bf16(xf[ks], wf, acc[j], 0, 0, 0);
            }
        }

        const long bb = mbase >> 11;          // batch
        const long tloc = mbase & 2047;       // token within batch

#pragma unroll
        for (int j = 0; j < 4; ++j) {         // Q/K: lane owns token
            const int nb = j * 4 + w;
            const int c0 = nb * 16 + grp * 4;
            const float4 bias = *(const float4*)&bqkv[c0];
            const int local = c0 & 127;
            const int h = local >> 5, d0 = local & 31;
            __hip_bfloat16* dst = (j < 2) ? Qb : Kb;
            const float sc = (j < 2) ? QSCALE_ : 1.f;
            const long t = tloc + qi;
            u32x2 pw;
            pw.x = pack2bf((acc[j][0] + bias.x) * sc, (acc[j][1] + bias.y) * sc);
            pw.y = pack2bf((acc[j][2] + bias.z) * sc, (acc[j][3] + bias.w) * sc);
            *(u32x2*)&dst[((bb * H_ + h) * T_ + t) * DH_ + d0] = pw;
        }
#pragma unroll
        for (int j = 4; j < 6; ++j) {         // V: lane owns col d
            const int nb = j * 4 + w;
            const int c = nb * 16 + qi;
            const int local = c - 256;
            const int h = local >> 5, d = local & 31;
            const float bias = bqkv[c];
            const long t0 = tloc + grp * 4;
            const long u = t0 >> 5;
            const long sin = t0 & 31;
            u32x2 pw;
            pw.x = pack2bf(acc[j][0] + bias, acc[j][1] + bias);
            pw.y = pack2bf(acc[j][2] + bias, acc[j][3] + bias);
            *(u32x2*)&Vt[(((bb * H_ + h) * 64 + u) * 32 + d) * 32 + sin] = pw;
        }
    }
    gridbar(bar, bar + 1);

    // ================= phase 2: attention + out-projection ================
    {
        const int half = tid >> 9;            // 0 = heavy chunk, 1 = light
        const int t5   = tid & 511;
        const int b    = bid & 7;
        const int k    = bid >> 3;            // 0..31
        const int c    = half ? k : 63 - k;   // paired: 65 units per block

        const int w    = t5 >> 6;             // 0..7
        const int h    = w & 3;               // head
        const int e    = w >> 2;              // s-parity
        const int lane = t5 & 63;
        const int ql   = lane & 31;
        const int hi   = lane >> 5;
        const int hi4  = hi * 4;
        const int hi8  = hi * 8;

        const int bh = b * H_ + h;
        const int q  = c * 32 + ql;

        const __hip_bfloat16* Qp = Qb + (size_t)bh * T_ * DH_;
        const __hip_bfloat16* Kp = Kb + (size_t)bh * T_ * DH_;
        const __hip_bfloat16* Vp = Vt + (size_t)bh * 64 * 1024;   // tiled [u][32d][32s]

        const bfrag qf0 = *(const bfrag*)(Qp + q * DH_ + hi8);
        const bfrag qf1 = *(const bfrag*)(Qp + q * DH_ + 16 + hi8);

        f32x16 o;
#pragma unroll
        for (int r = 0; r < 16; ++r) o[r] = 0.f;
        float l = 0.f;

        auto ldK = [&](int u, bfrag& k0, bfrag& k1, bfrag& v0, bfrag& v1) {
            k0 = *(const bfrag*)(Kp + (u * 32 + ql) * DH_ + hi8);
            k1 = *(const bfrag*)(Kp + (u * 32 + ql) * DH_ + 16 + hi8);
            const __hip_bfloat16* vb = Vp + u * 1024 + ql * 32;
            v0 = *(const bfrag*)(vb + hi8);
            v1 = *(const bfrag*)(vb + 16 + hi8);
        };

        auto proc = [&](const bfrag& kf0, const bfrag& kf1, const bfrag& vf0,
                        const bfrag& vf1, int sbase, bool band) {
            f32x16 s;
#pragma unroll
            for (int r = 0; r < 16; ++r) s[r] = 0.f;
            s = __builtin_amdgcn_mfma_f32_32x32x16_bf16(kf0, qf0, s, 0, 0, 0);
            s = __builtin_amdgcn_mfma_f32_32x32x16_bf16(kf1, qf1, s, 0, 0, 0);
            if (band) {
#pragma unroll
                for (int r = 0; r < 16; ++r) {
                    const int srow = sbase + (r & 3) + 8 * (r >> 2) + hi4;
                    if (srow > q) s[r] = -INFINITY;
                }
            }
#pragma unroll
            for (int r = 0; r < 16; ++r) { s[r] = fast_exp2(s[r]); l += s[r]; }
            u32x4 w0, w1;
            {
                unsigned a0 = cvtpk_bf16(s[0], s[1]);
                unsigned a1 = cvtpk_bf16(s[2], s[3]);
                unsigned a2 = cvtpk_bf16(s[4], s[5]);
                unsigned a3 = cvtpk_bf16(s[6], s[7]);
                auto r02 = __builtin_amdgcn_permlane32_swap((int)a0, (int)a2, false, false);
                auto r13 = __builtin_amdgcn_permlane32_swap((int)a1, (int)a3, false, false);
                w0.x = (unsigned)r02[0]; w0.y = (unsigned)r13[0];
                w0.z = (unsigned)r02[1]; w0.w = (unsigned)r13[1];
            }
            {
                unsigned a0 = cvtpk_bf16(s[8],  s[9]);
                unsigned a1 = cvtpk_bf16(s[10], s[11]);
                unsigned a2 = cvtpk_bf16(s[12], s[13]);
                unsigned a3 = cvtpk_bf16(s[14], s[15]);
                auto r02 = __builtin_amdgcn_permlane32_swap((int)a0, (int)a2, false, false);
                auto r13 = __builtin_amdgcn_permlane32_swap((int)a1, (int)a3, false, false);
                w1.x = (unsigned)r02[0]; w1.y = (unsigned)r13[0];
                w1.z = (unsigned)r02[1]; w1.w = (unsigned)r13[1];
            }
            o = __builtin_amdgcn_mfma_f32_32x32x16_bf16(
                    vf0, __builtin_bit_cast(bfrag, w0), o, 0, 0, 0);
            o = __builtin_amdgcn_mfma_f32_32x32x16_bf16(
                    vf1, __builtin_bit_cast(bfrag, w1), o, 0, 0, 0);
        };

        // attention over units u = e, e+2, ... <= c (2-deep ping-pong)
        if (e <= c) {
            bfrag ck0, ck1, cv0, cv1, nk0, nk1, nv0, nv1;
            ldK(e, ck0, ck1, cv0, cv1);
            for (int u = e; u <= c; u += 2) {
                if (u + 2 <= c) ldK(u + 2, nk0, nk1, nv0, nv1);
                proc(ck0, ck1, cv0, cv1, u * 32, u == c);
                ck0 = nk0; ck1 = nk1; cv0 = nv0; cv1 = nv1;
            }
        }

        // merge the two hi-halves' l (same q, disjoint s rows)
        l += __shfl_xor(l, 32);

        // parity combine (fixed-max softmax -> plain sums)
        if (e == 1) {
            float* my = &csm[half][h][lane][0];
            f32x4 t0 = {o[0], o[1], o[2], o[3]};
            f32x4 t1 = {o[4], o[5], o[6], o[7]};
            f32x4 t2 = {o[8], o[9], o[10], o[11]};
            f32x4 t3 = {o[12], o[13], o[14], o[15]};
            *(f32x4*)(my + 0) = t0;  *(f32x4*)(my + 4) = t1;
            *(f32x4*)(my + 8) = t2;  *(f32x4*)(my + 12) = t3;
            my[16] = l;
        }
        __syncthreads();
        if (e == 0) {
            const float* pr = &csm[half][h][lane][0];
#pragma unroll
            for (int r = 0; r < 16; ++r) o[r] += pr[r];
            l += pr[16];
            const float rl = 1.f / l;
#pragma unroll
            for (int pi = 0; pi < 8; ++pi) {
                const int r = pi * 2;
                const int n = (r & 3) + 8 * (r >> 2) + hi4;      // dim within head
                Osm[half][ql][(h * 32 + n) >> 1] = cvtpk_bf16(o[r] * rl, o[r + 1] * rl);
            }
        }
        __syncthreads();

        // output projection by the e==0 waves: wave h -> cols h*32..+31
        if (e == 0) {
            f32x16 acc;
#pragma unroll
            for (int r = 0; r < 16; ++r) acc[r] = 0.f;
#pragma unroll
            for (int ks = 0; ks < 8; ++ks) {
                const bfrag wf = *(const bfrag*)(WoutT + (size_t)(h * 32 + ql) * 128 + ks * 16 + hi8);
                const u32x4 ofu = *(const u32x4*)&Osm[half][ql][ks * 8 + hi4];
                acc = __builtin_amdgcn_mfma_f32_32x32x16_bf16(
                          wf, __builtin_bit_cast(bfrag, ofu), acc, 0, 0, 0);
            }
            float* orow = out + ((size_t)b * T_ + c * 32 + ql) * 128 + h * 32;
#pragma unroll
            for (int pi = 0; pi < 8; ++pi) {
                const int r = pi * 2;
                const int n = (r & 3) + 8 * (r >> 2) + hi4;
                const float2 bb2 = *(const float2*)&bout[h * 32 + n];
                float2 ov;
                ov.x = acc[r] + bb2.x;
                ov.y = acc[r + 1] + bb2.y;
                *(float2*)&orow[n] = ov;
            }
        }
    }
}

// ---------------------------------------------------------------------------
extern "C" void kernel_launch(void* const* d_in, const int* in_sizes, int n_in,
                              void* d_out, int out_size, void* d_ws, size_t ws_size,
                              hipStream_t stream) {
    const float* x    = (const float*)d_in[0];
    const float* Wqkv = (const float*)d_in[1];
    const float* bqkv = (const float*)d_in[2];
    const float* Wout = (const float*)d_in[3];
    const float* bout = (const float*)d_in[4];
    float* out = (float*)d_out;

    const size_t per = (size_t)BH_ * T_ * DH_;   // 2,097,152 bf16 elems = 4 MB
    __hip_bfloat16* Qb    = (__hip_bfloat16*)d_ws;
    __hip_bfloat16* Kb    = Qb + per;
    __hip_bfloat16* Vt    = Kb + per;
    __hip_bfloat16* WqkvT = Vt + per;
    __hip_bfloat16* WoutT = WqkvT + 384 * 128;

    // barrier counters at a 32 MB offset (beyond all buffers), zeroed per call
    unsigned* bar = (unsigned*)((char*)d_ws + (32u << 20));
    hipMemsetAsync(bar, 0, 8, stream);

    mega<<<NBLK, 1024, 0, stream>>>(x, Wqkv, bqkv, Wout, bout,
                                    Qb, Kb, Vt, WqkvT, WoutT, out, bar);
}

// Round 14
// 58.631 us; speedup vs baseline: 1.7284x; 1.7284x over previous
//
#include <hip/hip_runtime.h>
#include <hip/hip_bf16.h>
#include <math.h>

// Problem constants
#define B_  8
#define T_  2048
#define C_  128
#define H_  4
#define DH_ 32
#define BH_ 32
#define NTOK 16384
// (1/sqrt(32)) * log2(e): scores come out in log2 domain -> softmax via exp2
#define QSCALE_ 0.25503486f

typedef __attribute__((ext_vector_type(8))) __bf16 bfrag;        // 4 VGPRs, MFMA A/B
typedef __attribute__((ext_vector_type(4))) float f32x4;
typedef __attribute__((ext_vector_type(16))) float f32x16;       // 32x32 MFMA C/D
typedef __attribute__((ext_vector_type(2))) unsigned int u32x2;
typedef __attribute__((ext_vector_type(4))) unsigned int u32x4;

__device__ __forceinline__ unsigned int pack2bf(float a, float b) {
    unsigned int ua = __float_as_uint(a);
    unsigned int ub = __float_as_uint(b);
    ua += 0x7fffu + ((ua >> 16) & 1u);   // RNE to bf16
    ub += 0x7fffu + ((ub >> 16) & 1u);
    return (ua >> 16) | (ub & 0xffff0000u);
}

// single-instruction packed f32x2 -> bf16x2 (RNE; no builtin on gfx950)
__device__ __forceinline__ unsigned int cvtpk_bf16(float lo, float hi) {
    unsigned int r;
    asm("v_cvt_pk_bf16_f32 %0, %1, %2" : "=v"(r) : "v"(lo), "v"(hi));
    return r;
}

// raw v_exp_f32 (2^x)
__device__ __forceinline__ float fast_exp2(float x) {
    float r;
    asm("v_exp_f32 %0, %1" : "=v"(r) : "v"(x));
    return r;
}

// ---------------------------------------------------------------------------
// Kernel 0: prep — transpose Wqkv -> WqkvT bf16 [384][128]; Wout -> WoutT
// bf16 [128][128]. 32 blocks. (unchanged from round 11)
// ---------------------------------------------------------------------------
__global__ __launch_bounds__(256)
void prep(const float* __restrict__ Wqkv, const float* __restrict__ Wout,
          __hip_bfloat16* __restrict__ WqkvT, __hip_bfloat16* __restrict__ WoutT) {
    const int bid = blockIdx.x;
    const int tid = threadIdx.x;
    if (bid < 24) {
        const int idx = bid * 256 + tid;             // 0..6143
        const int n = idx >> 4, k8 = idx & 15;
        float v[8];
#pragma unroll
        for (int i = 0; i < 8; ++i) v[i] = Wqkv[(k8 * 8 + i) * 384 + n];
        u32x4 pk;
        pk.x = pack2bf(v[0], v[1]); pk.y = pack2bf(v[2], v[3]);
        pk.z = pack2bf(v[4], v[5]); pk.w = pack2bf(v[6], v[7]);
        *(u32x4*)(WqkvT + n * 128 + k8 * 8) = pk;
    } else {
        const int idx = (bid - 24) * 256 + tid;      // 0..2047
        const int n = idx >> 4, k8 = idx & 15;
        float v[8];
#pragma unroll
        for (int i = 0; i < 8; ++i) v[i] = Wout[(k8 * 8 + i) * 128 + n];
        u32x4 pk;
        pk.x = pack2bf(v[0], v[1]); pk.y = pack2bf(v[2], v[3]);
        pk.z = pack2bf(v[4], v[5]); pk.w = pack2bf(v[6], v[7]);
        *(u32x4*)(WoutT + n * 128 + k8 * 8) = pk;
    }
}

// ---------------------------------------------------------------------------
// Kernel 1: MFMA QKV projection (unchanged from round 11).
// ---------------------------------------------------------------------------
__global__ __launch_bounds__(256)
void qkv_mfma(const float* __restrict__ x,
              const __hip_bfloat16* __restrict__ WT,
              const float* __restrict__ bqkv,
              __hip_bfloat16* __restrict__ Qb, __hip_bfloat16* __restrict__ Kb,
              __hip_bfloat16* __restrict__ Vt) {
    const int mbase = blockIdx.x * 16;
    const int w = threadIdx.x >> 6, lane = threadIdx.x & 63;
    const int qi = lane & 15, grp = lane >> 4;

    const f32x4 zero = {0.f, 0.f, 0.f, 0.f};
    f32x4 acc[6] = {zero, zero, zero, zero, zero, zero};

    const float* xrow = x + (size_t)(mbase + qi) * 128;
    bfrag xf[4];
#pragma unroll
    for (int ks = 0; ks < 4; ++ks) {
        const float4 a = *(const float4*)(xrow + ks * 32 + grp * 8);
        const float4 b = *(const float4*)(xrow + ks * 32 + grp * 8 + 4);
        u32x4 pk;
        pk.x = cvtpk_bf16(a.x, a.y);
        pk.y = cvtpk_bf16(a.z, a.w);
        pk.z = cvtpk_bf16(b.x, b.y);
        pk.w = cvtpk_bf16(b.z, b.w);
        xf[ks] = __builtin_bit_cast(bfrag, pk);
    }

#pragma unroll
    for (int j = 0; j < 6; ++j) {
        const int nb = j * 4 + w;
#pragma unroll
        for (int ks = 0; ks < 4; ++ks) {
            const bfrag wf = *(const bfrag*)(WT + (size_t)(nb * 16 + qi) * 128 + ks * 32 + grp * 8);
            if (j < 4) acc[j] = __builtin_amdgcn_mfma_f32_16x16x32_bf16(wf, xf[ks], acc[j], 0, 0, 0);
            else       acc[j] = __builtin_amdgcn_mfma_f32_16x16x32_bf16(xf[ks], wf, acc[j], 0, 0, 0);
        }
    }

    const long bb = mbase >> 11;        // batch
    const long tloc = mbase & 2047;     // token within batch

    // Q/K: lane owns token t = tloc+qi, regs are cols c0..c0+3
#pragma unroll
    for (int j = 0; j < 4; ++j) {
        const int nb = j * 4 + w;
        const int c0 = nb * 16 + grp * 4;
        const float4 bias = *(const float4*)&bqkv[c0];
        const int local = c0 & 127;
        const int h = local >> 5, d0 = local & 31;
        __hip_bfloat16* dst = (j < 2) ? Qb : Kb;
        const float sc = (j < 2) ? QSCALE_ : 1.f;
        const long t = tloc + qi;
        u32x2 pw;
        pw.x = pack2bf((acc[j][0] + bias.x) * sc, (acc[j][1] + bias.y) * sc);
        pw.y = pack2bf((acc[j][2] + bias.z) * sc, (acc[j][3] + bias.w) * sc);
        *(u32x2*)&dst[((bb * H_ + h) * T_ + t) * DH_ + d0] = pw;
    }
    // V: lane owns col c, regs are tokens tloc+grp*4 .. +3 (same 32-unit)
#pragma unroll
    for (int j = 4; j < 6; ++j) {
        const int nb = j * 4 + w;
        const int c = nb * 16 + qi;
        const int local = c - 256;
        const int h = local >> 5, d = local & 31;
        const float bias = bqkv[c];
        const long t0 = tloc + grp * 4;
        const long u = t0 >> 5;
        const long sin = t0 & 31;
        u32x2 pw;
        pw.x = pack2bf(acc[j][0] + bias, acc[j][1] + bias);
        pw.y = pack2bf(acc[j][2] + bias, acc[j][3] + bias);
        *(u32x2*)&Vt[(((bb * H_ + h) * 64 + u) * 32 + d) * 32 + sin] = pw;
    }
}

// ---------------------------------------------------------------------------
// Kernel 2: FUSED attention + out-projection, PAIRED chunks.
// Block = (b, pair p): chunks cA=p and cB=63-p -> every block does exactly
// 65 K/V unit-loads and 66 procs (self-balanced). 8 waves = 4 heads x 2
// s-parities; each wave loads K/V fragments ONCE per unit and procs both
// chunks (halves L2 fragment traffic; 2 independent MFMA chains per unit).
// Fixed-max softmax -> parity partials combine by plain sum in LDS.
// Out-projection uses all 8 waves: e=0 -> chunk A cols, e=1 -> chunk B cols.
// Grid 256 x 512 threads (1 block/CU).
// ---------------------------------------------------------------------------
__global__ __launch_bounds__(512)
void attn_out(const __hip_bfloat16* __restrict__ Qb,
              const __hip_bfloat16* __restrict__ Kb,
              const __hip_bfloat16* __restrict__ Vt,
              const __hip_bfloat16* __restrict__ WoutT,
              const float* __restrict__ bout, float* __restrict__ out) {
    __shared__ float csm[4][64][34];       // parity-1 partials A+B (34.8 KB)
    __shared__ unsigned int Osm[2][32][68];// normalized head outputs (17.4 KB)

    const int lin = blockIdx.x;            // 0..255
    const int b   = lin & 7;
    const int p   = lin >> 3;              // pair 0..31

    const int w    = threadIdx.x >> 6;     // 0..7
    const int h    = w & 3;                // head
    const int e    = w >> 2;               // s-parity
    const int lane = threadIdx.x & 63;
    const int ql   = lane & 31;
    const int hi   = lane >> 5;
    const int hi4  = hi * 4;
    const int hi8  = hi * 8;

    const int cA = p, cB = 63 - p;
    const int qA = cA * 32 + ql, qB = cB * 32 + ql;

    const int bh = b * H_ + h;
    const __hip_bfloat16* Qp = Qb + (size_t)bh * T_ * DH_;
    const __hip_bfloat16* Kp = Kb + (size_t)bh * T_ * DH_;
    const __hip_bfloat16* Vp = Vt + (size_t)bh * 64 * 1024;   // tiled [u][32d][32s]

    const bfrag qfA0 = *(const bfrag*)(Qp + qA * DH_ + hi8);
    const bfrag qfA1 = *(const bfrag*)(Qp + qA * DH_ + 16 + hi8);
    const bfrag qfB0 = *(const bfrag*)(Qp + qB * DH_ + hi8);
    const bfrag qfB1 = *(const bfrag*)(Qp + qB * DH_ + 16 + hi8);

    f32x16 oA, oB;
#pragma unroll
    for (int r = 0; r < 16; ++r) { oA[r] = 0.f; oB[r] = 0.f; }
    float lA = 0.f, lB = 0.f;

    auto ldK = [&](int u, bfrag& k0, bfrag& k1, bfrag& v0, bfrag& v1) {
        k0 = *(const bfrag*)(Kp + (u * 32 + ql) * DH_ + hi8);
        k1 = *(const bfrag*)(Kp + (u * 32 + ql) * DH_ + 16 + hi8);
        const __hip_bfloat16* vb = Vp + u * 1024 + ql * 32;
        v0 = *(const bfrag*)(vb + hi8);
        v1 = *(const bfrag*)(vb + 16 + hi8);
    };

    auto proc = [&](const bfrag& kf0, const bfrag& kf1, const bfrag& vf0,
                    const bfrag& vf1, int sbase, const bfrag& qf0,
                    const bfrag& qf1, int qg, bool band, f32x16& o, float& l) {
        f32x16 s;
#pragma unroll
        for (int r = 0; r < 16; ++r) s[r] = 0.f;
        s = __builtin_amdgcn_mfma_f32_32x32x16_bf16(kf0, qf0, s, 0, 0, 0);
        s = __builtin_amdgcn_mfma_f32_32x32x16_bf16(kf1, qf1, s, 0, 0, 0);
        if (band) {
#pragma unroll
            for (int r = 0; r < 16; ++r) {
                const int srow = sbase + (r & 3) + 8 * (r >> 2) + hi4;
                if (srow > qg) s[r] = -INFINITY;
            }
        }
#pragma unroll
        for (int r = 0; r < 16; ++r) { s[r] = fast_exp2(s[r]); l += s[r]; }
        u32x4 w0, w1;
        {
            unsigned a0 = cvtpk_bf16(s[0], s[1]);
            unsigned a1 = cvtpk_bf16(s[2], s[3]);
            unsigned a2 = cvtpk_bf16(s[4], s[5]);
            unsigned a3 = cvtpk_bf16(s[6], s[7]);
            auto r02 = __builtin_amdgcn_permlane32_swap((int)a0, (int)a2, false, false);
            auto r13 = __builtin_amdgcn_permlane32_swap((int)a1, (int)a3, false, false);
            w0.x = (unsigned)r02[0]; w0.y = (unsigned)r13[0];
            w0.z = (unsigned)r02[1]; w0.w = (unsigned)r13[1];
        }
        {
            unsigned a0 = cvtpk_bf16(s[8],  s[9]);
            unsigned a1 = cvtpk_bf16(s[10], s[11]);
            unsigned a2 = cvtpk_bf16(s[12], s[13]);
            unsigned a3 = cvtpk_bf16(s[14], s[15]);
            auto r02 = __builtin_amdgcn_permlane32_swap((int)a0, (int)a2, false, false);
            auto r13 = __builtin_amdgcn_permlane32_swap((int)a1, (int)a3, false, false);
            w1.x = (unsigned)r02[0]; w1.y = (unsigned)r13[0];
            w1.z = (unsigned)r02[1]; w1.w = (unsigned)r13[1];
        }
        o = __builtin_amdgcn_mfma_f32_32x32x16_bf16(
                vf0, __builtin_bit_cast(bfrag, w0), o, 0, 0, 0);
        o = __builtin_amdgcn_mfma_f32_32x32x16_bf16(
                vf1, __builtin_bit_cast(bfrag, w1), o, 0, 0, 0);
    };

    // ---- attention: units u = e, e+2, ... <= cB; K/V loaded once per unit
    {
        bfrag ck0, ck1, cv0, cv1, nk0, nk1, nv0, nv1;
        ldK(e, ck0, ck1, cv0, cv1);        // e <= 1 <= cB (cB >= 32) always
        for (int u = e; u <= cB; u += 2) {
            if (u + 2 <= cB) ldK(u + 2, nk0, nk1, nv0, nv1);
            proc(ck0, ck1, cv0, cv1, u * 32, qfB0, qfB1, qB, u == cB, oB, lB);
            if (u <= cA) proc(ck0, ck1, cv0, cv1, u * 32, qfA0, qfA1, qA, u == cA, oA, lA);
            ck0 = nk0; ck1 = nk1; cv0 = nv0; cv1 = nv1;
        }
    }

    // merge the two hi-halves' l (same q, disjoint s rows)
    lA += __shfl_xor(lA, 32);
    lB += __shfl_xor(lB, 32);

    // ---- parity combine (fixed-max softmax -> plain sums)
    if (e == 1) {
        float* my = &csm[h][lane][0];
        *(f32x4*)(my +  0) = f32x4{oA[0], oA[1], oA[2], oA[3]};
        *(f32x4*)(my +  4) = f32x4{oA[4], oA[5], oA[6], oA[7]};
        *(f32x4*)(my +  8) = f32x4{oA[8], oA[9], oA[10], oA[11]};
        *(f32x4*)(my + 12) = f32x4{oA[12], oA[13], oA[14], oA[15]};
        *(f32x4*)(my + 16) = f32x4{oB[0], oB[1], oB[2], oB[3]};
        *(f32x4*)(my + 20) = f32x4{oB[4], oB[5], oB[6], oB[7]};
        *(f32x4*)(my + 24) = f32x4{oB[8], oB[9], oB[10], oB[11]};
        *(f32x4*)(my + 28) = f32x4{oB[12], oB[13], oB[14], oB[15]};
        my[32] = lA;  my[33] = lB;
    }
    __syncthreads();
    if (e == 0) {
        const float* pr = &csm[h][lane][0];
#pragma unroll
        for (int r = 0; r < 16; ++r) { oA[r] += pr[r]; oB[r] += pr[16 + r]; }
        lA += pr[32];  lB += pr[33];
        const float rlA = 1.f / lA, rlB = 1.f / lB;
#pragma unroll
        for (int pi = 0; pi < 8; ++pi) {
            const int r = pi * 2;
            const int n = (r & 3) + 8 * (r >> 2) + hi4;      // dim within head
            Osm[0][ql][(h * 32 + n) >> 1] = cvtpk_bf16(oA[r] * rlA, oA[r + 1] * rlA);
            Osm[1][ql][(h * 32 + n) >> 1] = cvtpk_bf16(oB[r] * rlB, oB[r + 1] * rlB);
        }
    }
    __syncthreads();

    // ---- out-projection by ALL 8 waves: e selects the chunk
    {
        const int cc = e ? cB : cA;
        f32x16 acc;
#pragma unroll
        for (int r = 0; r < 16; ++r) acc[r] = 0.f;
#pragma unroll
        for (int ks = 0; ks < 8; ++ks) {
            const bfrag wf = *(const bfrag*)(WoutT + (size_t)(h * 32 + ql) * 128 + ks * 16 + hi8);
            const u32x4 ofu = *(const u32x4*)&Osm[e][ql][ks * 8 + hi4];
            acc = __builtin_amdgcn_mfma_f32_32x32x16_bf16(
                      wf, __builtin_bit_cast(bfrag, ofu), acc, 0, 0, 0);
        }
        float* orow = out + ((size_t)b * T_ + cc * 32 + ql) * 128 + h * 32;
#pragma unroll
        for (int pi = 0; pi < 8; ++pi) {
            const int r = pi * 2;
            const int n = (r & 3) + 8 * (r >> 2) + hi4;
            const float2 bb2 = *(const float2*)&bout[h * 32 + n];
            float2 ov;
            ov.x = acc[r] + bb2.x;
            ov.y = acc[r + 1] + bb2.y;
            *(float2*)&orow[n] = ov;
        }
    }
}

// ---------------------------------------------------------------------------
extern "C" void kernel_launch(void* const* d_in, const int* in_sizes, int n_in,
                              void* d_out, int out_size, void* d_ws, size_t ws_size,
                              hipStream_t stream) {
    const float* x    = (const float*)d_in[0];
    const float* Wqkv = (const float*)d_in[1];
    const float* bqkv = (const float*)d_in[2];
    const float* Wout = (const float*)d_in[3];
    const float* bout = (const float*)d_in[4];
    float* out = (float*)d_out;

    const size_t per = (size_t)BH_ * T_ * DH_;   // 2,097,152 bf16 elems = 4 MB
    __hip_bfloat16* Qb    = (__hip_bfloat16*)d_ws;
    __hip_bfloat16* Kb    = Qb + per;
    __hip_bfloat16* Vt    = Kb + per;
    __hip_bfloat16* WqkvT = Vt + per;
    __hip_bfloat16* WoutT = WqkvT + 384 * 128;

    prep<<<32, 256, 0, stream>>>(Wqkv, Wout, WqkvT, WoutT);

    qkv_mfma<<<NTOK / 16, 256, 0, stream>>>(x, WqkvT, bqkv, Qb, Kb, Vt);

    attn_out<<<256, 512, 0, stream>>>(Qb, Kb, Vt, WoutT, bout, out);
}

// Round 15
// 57.332 us; speedup vs baseline: 1.7676x; 1.0227x over previous
//
#include <hip/hip_runtime.h>
#include <hip/hip_bf16.h>
#include <math.h>

// Problem constants
#define B_  8
#define T_  2048
#define C_  128
#define H_  4
#define DH_ 32
#define BH_ 32
#define NTOK 16384
// (1/sqrt(32)) * log2(e): scores come out in log2 domain -> softmax via exp2
#define QSCALE_ 0.25503486f

typedef __attribute__((ext_vector_type(8))) __bf16 bfrag;        // 4 VGPRs, MFMA A/B
typedef __attribute__((ext_vector_type(4))) float f32x4;
typedef __attribute__((ext_vector_type(16))) float f32x16;       // 32x32 MFMA C/D
typedef __attribute__((ext_vector_type(2))) unsigned int u32x2;
typedef __attribute__((ext_vector_type(4))) unsigned int u32x4;

__device__ __forceinline__ unsigned int pack2bf(float a, float b) {
    unsigned int ua = __float_as_uint(a);
    unsigned int ub = __float_as_uint(b);
    ua += 0x7fffu + ((ua >> 16) & 1u);   // RNE to bf16
    ub += 0x7fffu + ((ub >> 16) & 1u);
    return (ua >> 16) | (ub & 0xffff0000u);
}

// single-instruction packed f32x2 -> bf16x2 (RNE; no builtin on gfx950)
__device__ __forceinline__ unsigned int cvtpk_bf16(float lo, float hi) {
    unsigned int r;
    asm("v_cvt_pk_bf16_f32 %0, %1, %2" : "=v"(r) : "v"(lo), "v"(hi));
    return r;
}

// raw v_exp_f32 (2^x)
__device__ __forceinline__ float fast_exp2(float x) {
    float r;
    asm("v_exp_f32 %0, %1" : "=v"(r) : "v"(x));
    return r;
}

// ---------------------------------------------------------------------------
// Kernel 0: prep — transpose Wqkv -> WqkvT bf16 [384][128]; Wout -> WoutT
// bf16 [128][128]. 32 blocks. (unchanged)
// ---------------------------------------------------------------------------
__global__ __launch_bounds__(256)
void prep(const float* __restrict__ Wqkv, const float* __restrict__ Wout,
          __hip_bfloat16* __restrict__ WqkvT, __hip_bfloat16* __restrict__ WoutT) {
    const int bid = blockIdx.x;
    const int tid = threadIdx.x;
    if (bid < 24) {
        const int idx = bid * 256 + tid;             // 0..6143
        const int n = idx >> 4, k8 = idx & 15;
        float v[8];
#pragma unroll
        for (int i = 0; i < 8; ++i) v[i] = Wqkv[(k8 * 8 + i) * 384 + n];
        u32x4 pk;
        pk.x = pack2bf(v[0], v[1]); pk.y = pack2bf(v[2], v[3]);
        pk.z = pack2bf(v[4], v[5]); pk.w = pack2bf(v[6], v[7]);
        *(u32x4*)(WqkvT + n * 128 + k8 * 8) = pk;
    } else {
        const int idx = (bid - 24) * 256 + tid;      // 0..2047
        const int n = idx >> 4, k8 = idx & 15;
        float v[8];
#pragma unroll
        for (int i = 0; i < 8; ++i) v[i] = Wout[(k8 * 8 + i) * 128 + n];
        u32x4 pk;
        pk.x = pack2bf(v[0], v[1]); pk.y = pack2bf(v[2], v[3]);
        pk.z = pack2bf(v[4], v[5]); pk.w = pack2bf(v[6], v[7]);
        *(u32x4*)(WoutT + n * 128 + k8 * 8) = pk;
    }
}

// ---------------------------------------------------------------------------
// Kernel 1: MFMA QKV projection (unchanged from round 11).
// ---------------------------------------------------------------------------
__global__ __launch_bounds__(256)
void qkv_mfma(const float* __restrict__ x,
              const __hip_bfloat16* __restrict__ WT,
              const float* __restrict__ bqkv,
              __hip_bfloat16* __restrict__ Qb, __hip_bfloat16* __restrict__ Kb,
              __hip_bfloat16* __restrict__ Vt) {
    const int mbase = blockIdx.x * 16;
    const int w = threadIdx.x >> 6, lane = threadIdx.x & 63;
    const int qi = lane & 15, grp = lane >> 4;

    const f32x4 zero = {0.f, 0.f, 0.f, 0.f};
    f32x4 acc[6] = {zero, zero, zero, zero, zero, zero};

    const float* xrow = x + (size_t)(mbase + qi) * 128;
    bfrag xf[4];
#pragma unroll
    for (int ks = 0; ks < 4; ++ks) {
        const float4 a = *(const float4*)(xrow + ks * 32 + grp * 8);
        const float4 b = *(const float4*)(xrow + ks * 32 + grp * 8 + 4);
        u32x4 pk;
        pk.x = cvtpk_bf16(a.x, a.y);
        pk.y = cvtpk_bf16(a.z, a.w);
        pk.z = cvtpk_bf16(b.x, b.y);
        pk.w = cvtpk_bf16(b.z, b.w);
        xf[ks] = __builtin_bit_cast(bfrag, pk);
    }

#pragma unroll
    for (int j = 0; j < 6; ++j) {
        const int nb = j * 4 + w;
#pragma unroll
        for (int ks = 0; ks < 4; ++ks) {
            const bfrag wf = *(const bfrag*)(WT + (size_t)(nb * 16 + qi) * 128 + ks * 32 + grp * 8);
            if (j < 4) acc[j] = __builtin_amdgcn_mfma_f32_16x16x32_bf16(wf, xf[ks], acc[j], 0, 0, 0);
            else       acc[j] = __builtin_amdgcn_mfma_f32_16x16x32_bf16(xf[ks], wf, acc[j], 0, 0, 0);
        }
    }

    const long bb = mbase >> 11;        // batch
    const long tloc = mbase & 2047;     // token within batch

    // Q/K: lane owns token t = tloc+qi, regs are cols c0..c0+3
#pragma unroll
    for (int j = 0; j < 4; ++j) {
        const int nb = j * 4 + w;
        const int c0 = nb * 16 + grp * 4;
        const float4 bias = *(const float4*)&bqkv[c0];
        const int local = c0 & 127;
        const int h = local >> 5, d0 = local & 31;
        __hip_bfloat16* dst = (j < 2) ? Qb : Kb;
        const float sc = (j < 2) ? QSCALE_ : 1.f;
        const long t = tloc + qi;
        u32x2 pw;
        pw.x = pack2bf((acc[j][0] + bias.x) * sc, (acc[j][1] + bias.y) * sc);
        pw.y = pack2bf((acc[j][2] + bias.z) * sc, (acc[j][3] + bias.w) * sc);
        *(u32x2*)&dst[((bb * H_ + h) * T_ + t) * DH_ + d0] = pw;
    }
    // V: lane owns col c, regs are tokens tloc+grp*4 .. +3 (same 32-unit)
#pragma unroll
    for (int j = 4; j < 6; ++j) {
        const int nb = j * 4 + w;
        const int c = nb * 16 + qi;
        const int local = c - 256;
        const int h = local >> 5, d = local & 31;
        const float bias = bqkv[c];
        const long t0 = tloc + grp * 4;
        const long u = t0 >> 5;
        const long sin = t0 & 31;
        u32x2 pw;
        pw.x = pack2bf(acc[j][0] + bias, acc[j][1] + bias);
        pw.y = pack2bf(acc[j][2] + bias, acc[j][3] + bias);
        *(u32x2*)&Vt[(((bb * H_ + h) * 64 + u) * 32 + d) * 32 + sin] = pw;
    }
}

// ---------------------------------------------------------------------------
// Kernel 2: FUSED attention + out-projection, PAIRED chunks, 16 waves/block.
// Block = (b, pair p): chunks cA=p, cB=63-p. 16 waves = 4 heads x 4
// s-parities (u = e, e+4, ...). K/V fragments loaded once per (head,unit);
// each load feeds both chunks. Fixed-max softmax -> parities 1..3 write
// partials to LDS, parity 0 reduces. Out-projection: e=0 -> chunk A,
// e=1 -> chunk B. Grid 256 x 1024 (1 block/CU, 16 waves/CU).
// LDS: 104.4 + 17.4 = 121.8 KB (fits the 160 KB 1-block/CU budget).
// ---------------------------------------------------------------------------
__global__ __launch_bounds__(1024)
void attn_out(const __hip_bfloat16* __restrict__ Qb,
              const __hip_bfloat16* __restrict__ Kb,
              const __hip_bfloat16* __restrict__ Vt,
              const __hip_bfloat16* __restrict__ WoutT,
              const float* __restrict__ bout, float* __restrict__ out) {
    __shared__ float csm[3][4][64][34];     // parity 1..3 partials (104.4 KB)
    __shared__ unsigned int Osm[2][32][68]; // normalized head outputs (17.4 KB)

    const int lin = blockIdx.x;            // 0..255
    const int b   = lin & 7;
    const int p   = lin >> 3;              // pair 0..31

    const int w    = threadIdx.x >> 6;     // 0..15
    const int h    = w & 3;                // head
    const int e    = w >> 2;               // s-parity 0..3
    const int lane = threadIdx.x & 63;
    const int ql   = lane & 31;
    const int hi   = lane >> 5;
    const int hi4  = hi * 4;
    const int hi8  = hi * 8;

    const int cA = p, cB = 63 - p;
    const int qA = cA * 32 + ql, qB = cB * 32 + ql;

    const int bh = b * H_ + h;
    const __hip_bfloat16* Qp = Qb + (size_t)bh * T_ * DH_;
    const __hip_bfloat16* Kp = Kb + (size_t)bh * T_ * DH_;
    const __hip_bfloat16* Vp = Vt + (size_t)bh * 64 * 1024;   // tiled [u][32d][32s]

    const bfrag qfA0 = *(const bfrag*)(Qp + qA * DH_ + hi8);
    const bfrag qfA1 = *(const bfrag*)(Qp + qA * DH_ + 16 + hi8);
    const bfrag qfB0 = *(const bfrag*)(Qp + qB * DH_ + hi8);
    const bfrag qfB1 = *(const bfrag*)(Qp + qB * DH_ + 16 + hi8);

    f32x16 oA, oB;
#pragma unroll
    for (int r = 0; r < 16; ++r) { oA[r] = 0.f; oB[r] = 0.f; }
    float lA = 0.f, lB = 0.f;

    auto ldK = [&](int u, bfrag& k0, bfrag& k1, bfrag& v0, bfrag& v1) {
        k0 = *(const bfrag*)(Kp + (u * 32 + ql) * DH_ + hi8);
        k1 = *(const bfrag*)(Kp + (u * 32 + ql) * DH_ + 16 + hi8);
        const __hip_bfloat16* vb = Vp + u * 1024 + ql * 32;
        v0 = *(const bfrag*)(vb + hi8);
        v1 = *(const bfrag*)(vb + 16 + hi8);
    };

    auto proc = [&](const bfrag& kf0, const bfrag& kf1, const bfrag& vf0,
                    const bfrag& vf1, int sbase, const bfrag& qf0,
                    const bfrag& qf1, int qg, bool band, f32x16& o, float& l) {
        f32x16 s;
#pragma unroll
        for (int r = 0; r < 16; ++r) s[r] = 0.f;
        s = __builtin_amdgcn_mfma_f32_32x32x16_bf16(kf0, qf0, s, 0, 0, 0);
        s = __builtin_amdgcn_mfma_f32_32x32x16_bf16(kf1, qf1, s, 0, 0, 0);
        if (band) {
#pragma unroll
            for (int r = 0; r < 16; ++r) {
                const int srow = sbase + (r & 3) + 8 * (r >> 2) + hi4;
                if (srow > qg) s[r] = -INFINITY;
            }
        }
#pragma unroll
        for (int r = 0; r < 16; ++r) { s[r] = fast_exp2(s[r]); l += s[r]; }
        u32x4 w0, w1;
        {
            unsigned a0 = cvtpk_bf16(s[0], s[1]);
            unsigned a1 = cvtpk_bf16(s[2], s[3]);
            unsigned a2 = cvtpk_bf16(s[4], s[5]);
            unsigned a3 = cvtpk_bf16(s[6], s[7]);
            auto r02 = __builtin_amdgcn_permlane32_swap((int)a0, (int)a2, false, false);
            auto r13 = __builtin_amdgcn_permlane32_swap((int)a1, (int)a3, false, false);
            w0.x = (unsigned)r02[0]; w0.y = (unsigned)r13[0];
            w0.z = (unsigned)r02[1]; w0.w = (unsigned)r13[1];
        }
        {
            unsigned a0 = cvtpk_bf16(s[8],  s[9]);
            unsigned a1 = cvtpk_bf16(s[10], s[11]);
            unsigned a2 = cvtpk_bf16(s[12], s[13]);
            unsigned a3 = cvtpk_bf16(s[14], s[15]);
            auto r02 = __builtin_amdgcn_permlane32_swap((int)a0, (int)a2, false, false);
            auto r13 = __builtin_amdgcn_permlane32_swap((int)a1, (int)a3, false, false);
            w1.x = (unsigned)r02[0]; w1.y = (unsigned)r13[0];
            w1.z = (unsigned)r02[1]; w1.w = (unsigned)r13[1];
        }
        o = __builtin_amdgcn_mfma_f32_32x32x16_bf16(
                vf0, __builtin_bit_cast(bfrag, w0), o, 0, 0, 0);
        o = __builtin_amdgcn_mfma_f32_32x32x16_bf16(
                vf1, __builtin_bit_cast(bfrag, w1), o, 0, 0, 0);
    };

    // ---- attention: units u = e, e+4, ... <= cB (e <= 3 < 32 <= cB always)
    {
        bfrag ck0, ck1, cv0, cv1, nk0, nk1, nv0, nv1;
        ldK(e, ck0, ck1, cv0, cv1);
        for (int u = e; u <= cB; u += 4) {
            if (u + 4 <= cB) ldK(u + 4, nk0, nk1, nv0, nv1);
            proc(ck0, ck1, cv0, cv1, u * 32, qfB0, qfB1, qB, u == cB, oB, lB);
            if (u <= cA) proc(ck0, ck1, cv0, cv1, u * 32, qfA0, qfA1, qA, u == cA, oA, lA);
            ck0 = nk0; ck1 = nk1; cv0 = nv0; cv1 = nv1;
        }
    }

    // merge the two hi-halves' l (same q, disjoint s rows)
    lA += __shfl_xor(lA, 32);
    lB += __shfl_xor(lB, 32);

    // ---- parity combine (fixed-max softmax -> plain sums)
    if (e >= 1) {
        float* my = &csm[e - 1][h][lane][0];
        *(f32x4*)(my +  0) = f32x4{oA[0], oA[1], oA[2], oA[3]};
        *(f32x4*)(my +  4) = f32x4{oA[4], oA[5], oA[6], oA[7]};
        *(f32x4*)(my +  8) = f32x4{oA[8], oA[9], oA[10], oA[11]};
        *(f32x4*)(my + 12) = f32x4{oA[12], oA[13], oA[14], oA[15]};
        *(f32x4*)(my + 16) = f32x4{oB[0], oB[1], oB[2], oB[3]};
        *(f32x4*)(my + 20) = f32x4{oB[4], oB[5], oB[6], oB[7]};
        *(f32x4*)(my + 24) = f32x4{oB[8], oB[9], oB[10], oB[11]};
        *(f32x4*)(my + 28) = f32x4{oB[12], oB[13], oB[14], oB[15]};
        my[32] = lA;  my[33] = lB;
    }
    __syncthreads();
    if (e == 0) {
#pragma unroll
        for (int pe = 0; pe < 3; ++pe) {
            const float* pr = &csm[pe][h][lane][0];
#pragma unroll
            for (int r = 0; r < 16; ++r) { oA[r] += pr[r]; oB[r] += pr[16 + r]; }
            lA += pr[32];  lB += pr[33];
        }
        const float rlA = 1.f / lA, rlB = 1.f / lB;
#pragma unroll
        for (int pi = 0; pi < 8; ++pi) {
            const int r = pi * 2;
            const int n = (r & 3) + 8 * (r >> 2) + hi4;      // dim within head
            Osm[0][ql][(h * 32 + n) >> 1] = cvtpk_bf16(oA[r] * rlA, oA[r + 1] * rlA);
            Osm[1][ql][(h * 32 + n) >> 1] = cvtpk_bf16(oB[r] * rlB, oB[r + 1] * rlB);
        }
    }
    __syncthreads();

    // ---- out-projection: e=0 -> chunk A, e=1 -> chunk B (e>=2 idle)
    if (e < 2) {
        const int cc = e ? cB : cA;
        f32x16 acc;
#pragma unroll
        for (int r = 0; r < 16; ++r) acc[r] = 0.f;
#pragma unroll
        for (int ks = 0; ks < 8; ++ks) {
            const bfrag wf = *(const bfrag*)(WoutT + (size_t)(h * 32 + ql) * 128 + ks * 16 + hi8);
            const u32x4 ofu = *(const u32x4*)&Osm[e][ql][ks * 8 + hi4];
            acc = __builtin_amdgcn_mfma_f32_32x32x16_bf16(
                      wf, __builtin_bit_cast(bfrag, ofu), acc, 0, 0, 0);
        }
        float* orow = out + ((size_t)b * T_ + cc * 32 + ql) * 128 + h * 32;
#pragma unroll
        for (int pi = 0; pi < 8; ++pi) {
            const int r = pi * 2;
            const int n = (r & 3) + 8 * (r >> 2) + hi4;
            const float2 bb2 = *(const float2*)&bout[h * 32 + n];
            float2 ov;
            ov.x = acc[r] + bb2.x;
            ov.y = acc[r + 1] + bb2.y;
            *(float2*)&orow[n] = ov;
        }
    }
}

// ---------------------------------------------------------------------------
extern "C" void kernel_launch(void* const* d_in, const int* in_sizes, int n_in,
                              void* d_out, int out_size, void* d_ws, size_t ws_size,
                              hipStream_t stream) {
    const float* x    = (const float*)d_in[0];
    const float* Wqkv = (const float*)d_in[1];
    const float* bqkv = (const float*)d_in[2];
    const float* Wout = (const float*)d_in[3];
    const float* bout = (const float*)d_in[4];
    float* out = (float*)d_out;

    const size_t per = (size_t)BH_ * T_ * DH_;   // 2,097,152 bf16 elems = 4 MB
    __hip_bfloat16* Qb    = (__hip_bfloat16*)d_ws;
    __hip_bfloat16* Kb    = Qb + per;
    __hip_bfloat16* Vt    = Kb + per;
    __hip_bfloat16* WqkvT = Vt + per;
    __hip_bfloat16* WoutT = WqkvT + 384 * 128;

    prep<<<32, 256, 0, stream>>>(Wqkv, Wout, WqkvT, WoutT);

    qkv_mfma<<<NTOK / 16, 256, 0, stream>>>(x, WqkvT, bqkv, Qb, Kb, Vt);

    attn_out<<<256, 1024, 0, stream>>>(Qb, Kb, Vt, WoutT, bout, out);
}

// Round 16
// 55.079 us; speedup vs baseline: 1.8398x; 1.0409x over previous
//
#include <hip/hip_runtime.h>
#include <hip/hip_bf16.h>
#include <math.h>

// Problem constants
#define B_  8
#define T_  2048
#define C_  128
#define H_  4
#define DH_ 32
#define BH_ 32
#define NTOK 16384
// (1/sqrt(32)) * log2(e): scores come out in log2 domain -> softmax via exp2
#define QSCALE_ 0.25503486f

// Fragment-blocked layouts: Kf/Qf/Vf[bh][blk][lane0..63][8 bf16]
//   K: blk = u*2 + kh      (u = s-unit, kh = k-half of DH; lane = s_row + ((k&15)>>3)*32)
//   Q: blk = chunk*2 + kh  (lane = q_col + ((k&15)>>3)*32)
//   V: blk = u*2 + sh      (sh = s-half; lane = d_row + ((s&15)>>3)*32)
// Each fragment load in attn = one contiguous 1KB wave read (16 lines, fully
// coalesced) instead of a 32-line 64B-stride gather.

typedef __attribute__((ext_vector_type(8))) __bf16 bfrag;        // 4 VGPRs, MFMA A/B
typedef __attribute__((ext_vector_type(4))) float f32x4;
typedef __attribute__((ext_vector_type(16))) float f32x16;       // 32x32 MFMA C/D
typedef __attribute__((ext_vector_type(2))) unsigned int u32x2;
typedef __attribute__((ext_vector_type(4))) unsigned int u32x4;

__device__ __forceinline__ unsigned int pack2bf(float a, float b) {
    unsigned int ua = __float_as_uint(a);
    unsigned int ub = __float_as_uint(b);
    ua += 0x7fffu + ((ua >> 16) & 1u);   // RNE to bf16
    ub += 0x7fffu + ((ub >> 16) & 1u);
    return (ua >> 16) | (ub & 0xffff0000u);
}

// single-instruction packed f32x2 -> bf16x2 (RNE; no builtin on gfx950)
__device__ __forceinline__ unsigned int cvtpk_bf16(float lo, float hi) {
    unsigned int r;
    asm("v_cvt_pk_bf16_f32 %0, %1, %2" : "=v"(r) : "v"(lo), "v"(hi));
    return r;
}

// raw v_exp_f32 (2^x)
__device__ __forceinline__ float fast_exp2(float x) {
    float r;
    asm("v_exp_f32 %0, %1" : "=v"(r) : "v"(x));
    return r;
}

// ---------------------------------------------------------------------------
// Kernel 0: prep — transpose Wqkv -> WqkvT bf16 [384][128]; Wout -> WoutT
// bf16 [128][128]. 32 blocks. (unchanged)
// ---------------------------------------------------------------------------
__global__ __launch_bounds__(256)
void prep(const float* __restrict__ Wqkv, const float* __restrict__ Wout,
          __hip_bfloat16* __restrict__ WqkvT, __hip_bfloat16* __restrict__ WoutT) {
    const int bid = blockIdx.x;
    const int tid = threadIdx.x;
    if (bid < 24) {
        const int idx = bid * 256 + tid;             // 0..6143
        const int n = idx >> 4, k8 = idx & 15;
        float v[8];
#pragma unroll
        for (int i = 0; i < 8; ++i) v[i] = Wqkv[(k8 * 8 + i) * 384 + n];
        u32x4 pk;
        pk.x = pack2bf(v[0], v[1]); pk.y = pack2bf(v[2], v[3]);
        pk.z = pack2bf(v[4], v[5]); pk.w = pack2bf(v[6], v[7]);
        *(u32x4*)(WqkvT + n * 128 + k8 * 8) = pk;
    } else {
        const int idx = (bid - 24) * 256 + tid;      // 0..2047
        const int n = idx >> 4, k8 = idx & 15;
        float v[8];
#pragma unroll
        for (int i = 0; i < 8; ++i) v[i] = Wout[(k8 * 8 + i) * 128 + n];
        u32x4 pk;
        pk.x = pack2bf(v[0], v[1]); pk.y = pack2bf(v[2], v[3]);
        pk.z = pack2bf(v[4], v[5]); pk.w = pack2bf(v[6], v[7]);
        *(u32x4*)(WoutT + n * 128 + k8 * 8) = pk;
    }
}

// ---------------------------------------------------------------------------
// Kernel 1: MFMA QKV projection; MFMA core unchanged from round 11, stores
// retargeted to the fragment-blocked Qf/Kf/Vf layouts (still one 8B store
// per reg-pair; per-wave store pattern = contiguous 256B runs).
// ---------------------------------------------------------------------------
__global__ __launch_bounds__(256)
void qkv_mfma(const float* __restrict__ x,
              const __hip_bfloat16* __restrict__ WT,
              const float* __restrict__ bqkv,
              __hip_bfloat16* __restrict__ Qf, __hip_bfloat16* __restrict__ Kf,
              __hip_bfloat16* __restrict__ Vf) {
    const int mbase = blockIdx.x * 16;
    const int w = threadIdx.x >> 6, lane = threadIdx.x & 63;
    const int qi = lane & 15, grp = lane >> 4;

    const f32x4 zero = {0.f, 0.f, 0.f, 0.f};
    f32x4 acc[6] = {zero, zero, zero, zero, zero, zero};

    const float* xrow = x + (size_t)(mbase + qi) * 128;
    bfrag xf[4];
#pragma unroll
    for (int ks = 0; ks < 4; ++ks) {
        const float4 a = *(const float4*)(xrow + ks * 32 + grp * 8);
        const float4 b = *(const float4*)(xrow + ks * 32 + grp * 8 + 4);
        u32x4 pk;
        pk.x = cvtpk_bf16(a.x, a.y);
        pk.y = cvtpk_bf16(a.z, a.w);
        pk.z = cvtpk_bf16(b.x, b.y);
        pk.w = cvtpk_bf16(b.z, b.w);
        xf[ks] = __builtin_bit_cast(bfrag, pk);
    }

#pragma unroll
    for (int j = 0; j < 6; ++j) {
        const int nb = j * 4 + w;
#pragma unroll
        for (int ks = 0; ks < 4; ++ks) {
            const bfrag wf = *(const bfrag*)(WT + (size_t)(nb * 16 + qi) * 128 + ks * 32 + grp * 8);
            if (j < 4) acc[j] = __builtin_amdgcn_mfma_f32_16x16x32_bf16(wf, xf[ks], acc[j], 0, 0, 0);
            else       acc[j] = __builtin_amdgcn_mfma_f32_16x16x32_bf16(xf[ks], wf, acc[j], 0, 0, 0);
        }
    }

    const long bb = mbase >> 11;        // batch
    const long tloc = mbase & 2047;     // token within batch

    // Q/K: lane owns token t, regs = 4 consecutive d (d0 % 4 == 0)
#pragma unroll
    for (int j = 0; j < 4; ++j) {
        const int nb = j * 4 + w;
        const int c0 = nb * 16 + grp * 4;
        const float4 bias = *(const float4*)&bqkv[c0];
        const int local = c0 & 127;
        const int h = local >> 5, d0 = local & 31;
        __hip_bfloat16* dst = (j < 2) ? Qf : Kf;
        const float sc = (j < 2) ? QSCALE_ : 1.f;
        const long t = tloc + qi;              // token within batch (0..2047)
        const long bh = bb * H_ + h;
        const long blk = (bh * 64 + (t >> 5)) * 2 + (d0 >> 4);
        const int lanei = (int)(t & 31) + ((d0 & 15) >> 3) * 32;
        u32x2 pw;
        pw.x = pack2bf((acc[j][0] + bias.x) * sc, (acc[j][1] + bias.y) * sc);
        pw.y = pack2bf((acc[j][2] + bias.z) * sc, (acc[j][3] + bias.w) * sc);
        *(u32x2*)&dst[blk * 512 + lanei * 8 + (d0 & 7)] = pw;
    }
    // V: lane owns row d, regs = 4 consecutive s (s0 % 4 == 0)
#pragma unroll
    for (int j = 4; j < 6; ++j) {
        const int nb = j * 4 + w;
        const int c = nb * 16 + qi;
        const int local = c - 256;
        const int h = local >> 5, d = local & 31;
        const float bias = bqkv[c];
        const long t0 = tloc + grp * 4;        // s token (0..2047)
        const long bh = bb * H_ + h;
        const int s0 = (int)(t0 & 31);
        const long blk = (bh * 64 + (t0 >> 5)) * 2 + (s0 >> 4);
        const int lanei = d + ((s0 & 15) >> 3) * 32;
        u32x2 pw;
        pw.x = pack2bf(acc[j][0] + bias, acc[j][1] + bias);
        pw.y = pack2bf(acc[j][2] + bias, acc[j][3] + bias);
        *(u32x2*)&Vf[blk * 512 + lanei * 8 + (s0 & 7)] = pw;
    }
}

// ---------------------------------------------------------------------------
// Kernel 2: FUSED attention + out-projection (round-11 structure verbatim);
// only the fragment load addressing changed to the blocked layouts: every
// K/V/Q fragment load is one contiguous 1KB wave read.
// Block = (b, chunk c); 8 waves = 4 heads x 2 s-parities. Grid 512 x 512.
// ---------------------------------------------------------------------------
__global__ __launch_bounds__(512, 4)
void attn_out(const __hip_bfloat16* __restrict__ Qf,
              const __hip_bfloat16* __restrict__ Kf,
              const __hip_bfloat16* __restrict__ Vf,
              const __hip_bfloat16* __restrict__ WoutT,
              const float* __restrict__ bout, float* __restrict__ out) {
    __shared__ float csm[4][64][17];       // parity-1 partials (17.4 KB)
    __shared__ unsigned int Osm[32][68];   // bf16-pair rows (8.7 KB)

    const int lin = blockIdx.x;            // 0..511
    int b, c;
    if (lin < 256) { b = lin & 7; c = 63 - (lin >> 3); }     // heavy half
    else { const int m = lin - 256; b = m & 7; c = m >> 3; } // light half

    const int w    = threadIdx.x >> 6;     // 0..7
    const int h    = w & 3;                // head
    const int e    = w >> 2;               // s-parity
    const int lane = threadIdx.x & 63;
    const int ql   = lane & 31;
    const int hi   = lane >> 5;
    const int hi4  = hi * 4;

    const int bh = b * H_ + h;
    const int q  = c * 32 + ql;

    const __hip_bfloat16* Qp = Qf + (size_t)bh * 64 * 1024;   // 64 blk-pairs
    const __hip_bfloat16* Kp = Kf + (size_t)bh * 64 * 1024;
    const __hip_bfloat16* Vp = Vf + (size_t)bh * 64 * 1024;

    const bfrag qf0 = *(const bfrag*)(Qp + (c * 2 + 0) * 512 + lane * 8);
    const bfrag qf1 = *(const bfrag*)(Qp + (c * 2 + 1) * 512 + lane * 8);

    f32x16 o;
#pragma unroll
    for (int r = 0; r < 16; ++r) o[r] = 0.f;
    float l = 0.f;

    auto ldK = [&](int u, bfrag& k0, bfrag& k1, bfrag& v0, bfrag& v1) {
        k0 = *(const bfrag*)(Kp + (u * 2 + 0) * 512 + lane * 8);
        k1 = *(const bfrag*)(Kp + (u * 2 + 1) * 512 + lane * 8);
        v0 = *(const bfrag*)(Vp + (u * 2 + 0) * 512 + lane * 8);
        v1 = *(const bfrag*)(Vp + (u * 2 + 1) * 512 + lane * 8);
    };

    auto proc = [&](const bfrag& kf0, const bfrag& kf1, const bfrag& vf0,
                    const bfrag& vf1, int sbase, bool band) {
        f32x16 s;
#pragma unroll
        for (int r = 0; r < 16; ++r) s[r] = 0.f;
        s = __builtin_amdgcn_mfma_f32_32x32x16_bf16(kf0, qf0, s, 0, 0, 0);
        s = __builtin_amdgcn_mfma_f32_32x32x16_bf16(kf1, qf1, s, 0, 0, 0);
        if (band) {
#pragma unroll
            for (int r = 0; r < 16; ++r) {
                const int srow = sbase + (r & 3) + 8 * (r >> 2) + hi4;
                if (srow > q) s[r] = -INFINITY;
            }
        }
#pragma unroll
        for (int r = 0; r < 16; ++r) { s[r] = fast_exp2(s[r]); l += s[r]; }
        u32x4 w0, w1;
        {
            unsigned a0 = cvtpk_bf16(s[0], s[1]);
            unsigned a1 = cvtpk_bf16(s[2], s[3]);
            unsigned a2 = cvtpk_bf16(s[4], s[5]);
            unsigned a3 = cvtpk_bf16(s[6], s[7]);
            auto r02 = __builtin_amdgcn_permlane32_swap((int)a0, (int)a2, false, false);
            auto r13 = __builtin_amdgcn_permlane32_swap((int)a1, (int)a3, false, false);
            w0.x = (unsigned)r02[0]; w0.y = (unsigned)r13[0];
            w0.z = (unsigned)r02[1]; w0.w = (unsigned)r13[1];
        }
        {
            unsigned a0 = cvtpk_bf16(s[8],  s[9]);
            unsigned a1 = cvtpk_bf16(s[10], s[11]);
            unsigned a2 = cvtpk_bf16(s[12], s[13]);
            unsigned a3 = cvtpk_bf16(s[14], s[15]);
            auto r02 = __builtin_amdgcn_permlane32_swap((int)a0, (int)a2, false, false);
            auto r13 = __builtin_amdgcn_permlane32_swap((int)a1, (int)a3, false, false);
            w1.x = (unsigned)r02[0]; w1.y = (unsigned)r13[0];
            w1.z = (unsigned)r02[1]; w1.w = (unsigned)r13[1];
        }
        o = __builtin_amdgcn_mfma_f32_32x32x16_bf16(
                vf0, __builtin_bit_cast(bfrag, w0), o, 0, 0, 0);
        o = __builtin_amdgcn_mfma_f32_32x32x16_bf16(
                vf1, __builtin_bit_cast(bfrag, w1), o, 0, 0, 0);
    };

    // ---- attention over units u = e, e+2, ... <= c (2-deep ping-pong)
    if (e <= c) {
        bfrag ck0, ck1, cv0, cv1, nk0, nk1, nv0, nv1;
        ldK(e, ck0, ck1, cv0, cv1);
        for (int u = e; u <= c; u += 2) {
            if (u + 2 <= c) ldK(u + 2, nk0, nk1, nv0, nv1);
            proc(ck0, ck1, cv0, cv1, u * 32, u == c);
            ck0 = nk0; ck1 = nk1; cv0 = nv0; cv1 = nv1;
        }
    }

    // merge the two hi-halves' l (same q, disjoint s rows)
    l += __shfl_xor(l, 32);

    // ---- parity combine (fixed-max softmax -> plain sums)
    if (e == 1) {
        float* my = &csm[h][lane][0];
        f32x4 t0 = {o[0], o[1], o[2], o[3]};
        f32x4 t1 = {o[4], o[5], o[6], o[7]};
        f32x4 t2 = {o[8], o[9], o[10], o[11]};
        f32x4 t3 = {o[12], o[13], o[14], o[15]};
        *(f32x4*)(my + 0) = t0;  *(f32x4*)(my + 4) = t1;
        *(f32x4*)(my + 8) = t2;  *(f32x4*)(my + 12) = t3;
        my[16] = l;
    }
    __syncthreads();
    if (e == 0) {
        const float* pr = &csm[h][lane][0];
#pragma unroll
        for (int r = 0; r < 16; ++r) o[r] += pr[r];
        l += pr[16];
        const float rl = 1.f / l;
#pragma unroll
        for (int pi = 0; pi < 8; ++pi) {
            const int r = pi * 2;
            const int n = (r & 3) + 8 * (r >> 2) + hi4;      // dim within head
            Osm[ql][(h * 32 + n) >> 1] = cvtpk_bf16(o[r] * rl, o[r + 1] * rl);
        }
    }
    __syncthreads();

    // ---- output projection by the 4 e==0 waves: wave h -> cols h*32..+31
    if (e == 0) {
        const int hi8 = hi * 8;
        f32x16 acc;
#pragma unroll
        for (int r = 0; r < 16; ++r) acc[r] = 0.f;
#pragma unroll
        for (int ks = 0; ks < 8; ++ks) {
            const bfrag wf = *(const bfrag*)(WoutT + (size_t)(h * 32 + ql) * 128 + ks * 16 + hi8);
            const u32x4 ofu = *(const u32x4*)&Osm[ql][ks * 8 + hi4];
            acc = __builtin_amdgcn_mfma_f32_32x32x16_bf16(
                      wf, __builtin_bit_cast(bfrag, ofu), acc, 0, 0, 0);
        }
        float* orow = out + ((size_t)b * T_ + c * 32 + ql) * 128 + h * 32;
#pragma unroll
        for (int pi = 0; pi < 8; ++pi) {
            const int r = pi * 2;
            const int n = (r & 3) + 8 * (r >> 2) + hi4;
            const float2 bb2 = *(const float2*)&bout[h * 32 + n];
            float2 ov;
            ov.x = acc[r] + bb2.x;
            ov.y = acc[r + 1] + bb2.y;
            *(float2*)&orow[n] = ov;
        }
    }
}

// ---------------------------------------------------------------------------
extern "C" void kernel_launch(void* const* d_in, const int* in_sizes, int n_in,
                              void* d_out, int out_size, void* d_ws, size_t ws_size,
                              hipStream_t stream) {
    const float* x    = (const float*)d_in[0];
    const float* Wqkv = (const float*)d_in[1];
    const float* bqkv = (const float*)d_in[2];
    const float* Wout = (const float*)d_in[3];
    const float* bout = (const float*)d_in[4];
    float* out = (float*)d_out;

    const size_t per = (size_t)BH_ * T_ * DH_;   // 2,097,152 bf16 elems = 4 MB
    __hip_bfloat16* Qf    = (__hip_bfloat16*)d_ws;
    __hip_bfloat16* Kf    = Qf + per;
    __hip_bfloat16* Vf    = Kf + per;
    __hip_bfloat16* WqkvT = Vf + per;
    __hip_bfloat16* WoutT = WqkvT + 384 * 128;

    prep<<<32, 256, 0, stream>>>(Wqkv, Wout, WqkvT, WoutT);

    qkv_mfma<<<NTOK / 16, 256, 0, stream>>>(x, WqkvT, bqkv, Qf, Kf, Vf);

    attn_out<<<512, 512, 0, stream>>>(Qf, Kf, Vf, WoutT, bout, out);
}